// Round 2
// baseline (747.637 us; speedup 1.0000x reference)
//
#include <hip/hip_runtime.h>
#include <hip/hip_bf16.h>

// StrassenMHA on MI355X — round 2: f32 baseline, f32 OUTPUT (round-1 failure
// was writing bf16 into an f32 d_out; threshold arithmetic proved f32).
// B=2, N=256, DIM=512, H=8, DH=64.

namespace {
constexpr int kB = 2, kN = 256, kH = 8, kDH = 64;
constexpr int kBH = kB * kH;     // 16
constexpr int kBN = kB * kN;     // 512
constexpr int kDIM = 512;
constexpr int kQKV = 2560;
constexpr float kScale = 0.125f; // DH^-0.5
constexpr float kClamp = 40.0f;
constexpr float kEps = 1.1920928955078125e-07f; // finfo(f32).eps

// ws layout (float element offsets).
// Region 0 (1,310,720 floats) holds qkv first; after rms_layout consumes it,
// E1 (1,048,576) and attn (262,144) are overlaid there — stream-ordered safe.
constexpr size_t OF_QKV  = 0;                                   // 512*2560
constexpr size_t OF_E1   = 0;                                   // overlays qkv
constexpr size_t OF_ATTN = OF_E1 + (size_t)kBH * kN * kN;       // 1,048,576
constexpr size_t OF_Q    = (size_t)kBN * kQKV;                  // 1,310,720
constexpr size_t OF_K1   = OF_Q    + (size_t)kBH * kN * kDH;
constexpr size_t OF_K2   = OF_K1   + (size_t)kBH * kN * kDH;
constexpr size_t OF_V1   = OF_K2   + (size_t)kBH * kN * kDH;
constexpr size_t OF_V2   = OF_V1   + (size_t)kBH * kN * kDH;
constexpr size_t OF_E2   = OF_V2   + (size_t)kBH * kN * kDH;    // 2,621,440
constexpr size_t OF_E3   = OF_E2   + (size_t)kBH * kN * kN;
constexpr size_t OF_NUM  = OF_E3   + (size_t)kBH * kN * kN;
constexpr size_t OF_DEN  = OF_NUM  + (size_t)kBH * kN * kDH;
// total = 4,984,832 floats = 19.94 MB of d_ws
} // namespace

// ---------------------------------------------------------------- GEMM f32
// C[M][N] = A[M][K] @ B[K][N], 64x64 tile, 4x4 per thread, K-chunk 16.
__global__ __launch_bounds__(256)
void gemm_f32(const float* __restrict__ A, const float* __restrict__ Bm,
              float* __restrict__ C, int M, int N, int K) {
  __shared__ __align__(16) float As[16][68];  // [k][m]
  __shared__ __align__(16) float Bs[16][68];  // [k][n]
  const int tx = threadIdx.x & 15, ty = threadIdx.x >> 4;
  const int n0 = blockIdx.x * 64, m0 = blockIdx.y * 64;
  float acc[4][4] = {};
  for (int k0 = 0; k0 < K; k0 += 16) {
    {
      const int m = threadIdx.x >> 2;
      const int kk = (threadIdx.x & 3) << 2;
      float4 v = *(const float4*)(A + (size_t)(m0 + m) * K + k0 + kk);
      As[kk + 0][m] = v.x; As[kk + 1][m] = v.y;
      As[kk + 2][m] = v.z; As[kk + 3][m] = v.w;
    }
    {
      const int kk = threadIdx.x >> 4;
      const int n = (threadIdx.x & 15) << 2;
      *(float4*)&Bs[kk][n] = *(const float4*)(Bm + (size_t)(k0 + kk) * N + n0 + n);
    }
    __syncthreads();
#pragma unroll
    for (int kk = 0; kk < 16; ++kk) {
      float4 a4 = *(const float4*)&As[kk][ty << 2];
      float4 b4 = *(const float4*)&Bs[kk][tx << 2];
      const float av[4] = {a4.x, a4.y, a4.z, a4.w};
      const float bv[4] = {b4.x, b4.y, b4.z, b4.w};
#pragma unroll
      for (int i = 0; i < 4; ++i)
#pragma unroll
        for (int j = 0; j < 4; ++j)
          acc[i][j] = fmaf(av[i], bv[j], acc[i][j]);
    }
    __syncthreads();
  }
#pragma unroll
  for (int i = 0; i < 4; ++i) {
    float* cp = C + (size_t)(m0 + (ty << 2) + i) * N + n0 + (tx << 2);
#pragma unroll
    for (int j = 0; j < 4; ++j) cp[j] = acc[i][j];
  }
}

// ------------------------------------------------- RMSNorm + head split
__global__ __launch_bounds__(64)
void rms_layout(const float* __restrict__ qkv,
                const float* __restrict__ wq, const float* __restrict__ wk1,
                const float* __restrict__ wk2,
                float* __restrict__ Q, float* __restrict__ K1,
                float* __restrict__ K2, float* __restrict__ V1,
                float* __restrict__ V2) {
  const int bnh = blockIdx.x;           // (b*N+n)*H + h
  const int h = bnh & 7;
  const int bn = bnh >> 3;              // 0..511
  const int b = bn >> 8;
  const int n = bn & 255;
  const int d = threadIdx.x;            // 0..63
  const float* row = qkv + (size_t)bn * kQKV;
  const int base = h * 64 + d;
  float q  = row[0 * 512 + base];
  float k1 = row[1 * 512 + base];
  float k2 = row[2 * 512 + base];
  float v1 = row[3 * 512 + base];
  float v2 = row[4 * 512 + base];
  float sq = q * q, s1 = k1 * k1, s2 = k2 * k2;
#pragma unroll
  for (int m = 32; m >= 1; m >>= 1) {
    sq += __shfl_xor(sq, m);
    s1 += __shfl_xor(s1, m);
    s2 += __shfl_xor(s2, m);
  }
  const float rq = rsqrtf(sq * (1.0f / 64) + kEps);
  const float r1 = rsqrtf(s1 * (1.0f / 64) + kEps);
  const float r2 = rsqrtf(s2 * (1.0f / 64) + kEps);
  const int bh = b * kH + h;
  const size_t o = ((size_t)bh * kN + n) * kDH + d;
  Q[o]  = q * rq * wq[d];
  K1[o] = k1 * r1 * wk1[d];
  K2[o] = k2 * r2 * wk2[d];
  V1[o] = v1;
  V2[o] = v2;
}

// ------------------------------------------------- E = exp(clip(dot/8))
// type 0: Q.K1 -> E1 ; type 1: Q.K2 -> E2 ; type 2: K1.K2 -> E3
__global__ __launch_bounds__(256)
void sims_exp(const float* __restrict__ Q, const float* __restrict__ K1,
              const float* __restrict__ K2, float* __restrict__ E1,
              float* __restrict__ E2, float* __restrict__ E3) {
  __shared__ __align__(16) float As[64][68];  // [k][i]
  __shared__ __align__(16) float Bs[64][68];  // [k][j]
  const int bh = blockIdx.x;
  const int type = blockIdx.y;
  const int i0 = (blockIdx.z >> 2) * 64;
  const int j0 = (blockIdx.z & 3) * 64;
  const float* Ap = (type == 2 ? K1 : Q) + ((size_t)bh * kN + i0) * kDH;
  const float* Bp = (type == 0 ? K1 : K2) + ((size_t)bh * kN + j0) * kDH;
  float* Ep = (type == 0 ? E1 : (type == 1 ? E2 : E3)) + (size_t)bh * kN * kN;
  const int t = threadIdx.x;
#pragma unroll
  for (int c = 0; c < 16; ++c) {
    int idx = c * 256 + t;
    int i = idx >> 6, k = idx & 63;
    As[k][i] = Ap[(size_t)i * kDH + k];
    Bs[k][i] = Bp[(size_t)i * kDH + k];
  }
  __syncthreads();
  const int tx = t & 15, ty = t >> 4;
  float acc[4][4] = {};
#pragma unroll 4
  for (int k = 0; k < 64; ++k) {
    float4 a4 = *(const float4*)&As[k][ty << 2];
    float4 b4 = *(const float4*)&Bs[k][tx << 2];
    const float av[4] = {a4.x, a4.y, a4.z, a4.w};
    const float bv[4] = {b4.x, b4.y, b4.z, b4.w};
#pragma unroll
    for (int i = 0; i < 4; ++i)
#pragma unroll
      for (int j = 0; j < 4; ++j)
        acc[i][j] = fmaf(av[i], bv[j], acc[i][j]);
  }
#pragma unroll
  for (int i = 0; i < 4; ++i) {
    float* ep = Ep + (size_t)(i0 + (ty << 2) + i) * kN + j0 + (tx << 2);
#pragma unroll
    for (int j = 0; j < 4; ++j) {
      float s = acc[i][j] * kScale;
      s = fminf(fmaxf(s, -kClamp), kClamp);
      ep[j] = expf(s);
    }
  }
}

// ---------------------------------------------------------- main contraction
// num[i,d] = sum_j e1[i,j] v1[j,d] * sum_k e2[i,k] e3[j,k] v2[k,d]
// den[i]   = sum_j e1[i,j]        * sum_k e2[i,k] e3[j,k]
// Block = (bh, i-tile 64, j-chunk 64). 4 waves: wave w owns 16 j's.
// Thread: 8x8 (i,d) register tile. k staged in 64-chunks in LDS.
__global__ __launch_bounds__(256, 1)
void strassen_main(const float* __restrict__ E1, const float* __restrict__ E2,
                   const float* __restrict__ E3, const float* __restrict__ V1,
                   const float* __restrict__ V2, float* __restrict__ NUMp,
                   float* __restrict__ DENp) {
  __shared__ __align__(16) float E2T[64][68];   // [k][i]
  __shared__ __align__(16) float V2L[64][68];   // [k][d]
  __shared__ float e3buf[4][64];                // per-wave e3 row chunk

  const int bid = blockIdx.x;
  const int jc = bid & 3;
  const int it = (bid >> 2) & 3;
  const int bh = bid >> 4;
  const int i0 = it * 64;
  const int t = threadIdx.x;
  const int lane = t & 63;
  const int w = t >> 6;
  const int ig = lane >> 3, dg = lane & 7;

  const float* e2p = E2 + ((size_t)bh * kN + i0) * kN;
  const float* e3p = E3 + (size_t)bh * kN * kN;
  const float* e1p = E1 + ((size_t)bh * kN + i0) * kN;
  const float* v1p = V1 + (size_t)bh * kN * kDH;
  const float* v2p = V2 + (size_t)bh * kN * kDH;

  float num[8][8] = {};
  float den[8] = {};

  for (int kc = 0; kc < 4; ++kc) {
    const int k0 = kc * 64;
    __syncthreads();  // protect LDS reuse across kc iterations
#pragma unroll
    for (int c = 0; c < 16; ++c) {
      int idx = c * 256 + t;
      int i = idx >> 6, k = idx & 63;
      E2T[k][i] = e2p[(size_t)i * kN + k0 + k];
      V2L[i][k] = v2p[(size_t)(k0 + i) * kDH + k];
    }
    __syncthreads();
    for (int jj = 0; jj < 16; ++jj) {
      const int j = jc * 64 + w * 16 + jj;
      e3buf[w][lane] = e3p[(size_t)j * kN + k0 + lane];  // same-wave RAW
      float C[8][8] = {};
      float dC[8] = {};
#pragma unroll 4
      for (int k = 0; k < 64; ++k) {
        const float e3k = e3buf[w][k];
        float a[8], v[8];
        *(float4*)&a[0] = *(const float4*)&E2T[k][ig * 8];
        *(float4*)&a[4] = *(const float4*)&E2T[k][ig * 8 + 4];
        *(float4*)&v[0] = *(const float4*)&V2L[k][dg * 8];
        *(float4*)&v[4] = *(const float4*)&V2L[k][dg * 8 + 4];
#pragma unroll
        for (int r = 0; r < 8; ++r) {
          const float ar = a[r] * e3k;
          dC[r] += ar;
#pragma unroll
          for (int c2 = 0; c2 < 8; ++c2)
            C[r][c2] = fmaf(ar, v[c2], C[r][c2]);
        }
      }
      float e1v[8], v1v[8];
#pragma unroll
      for (int r = 0; r < 8; ++r)
        e1v[r] = e1p[(size_t)(ig * 8 + r) * kN + j];
      *(float4*)&v1v[0] = *(const float4*)(v1p + (size_t)j * kDH + dg * 8);
      *(float4*)&v1v[4] = *(const float4*)(v1p + (size_t)j * kDH + dg * 8 + 4);
#pragma unroll
      for (int r = 0; r < 8; ++r) {
        den[r] = fmaf(e1v[r], dC[r], den[r]);
#pragma unroll
        for (int c2 = 0; c2 < 8; ++c2)
          num[r][c2] = fmaf(e1v[r] * v1v[c2], C[r][c2], num[r][c2]);
      }
    }
  }

  // reduce the 4 waves' partials into wave 0 then one atomicAdd per element
  __syncthreads();
  float* red0 = &E2T[0][0];
  float* red1 = &V2L[0][0];
  const int li = ig * 8 * 64 + dg * 8;
  if (w == 2) {
#pragma unroll
    for (int r = 0; r < 8; ++r)
#pragma unroll
      for (int c2 = 0; c2 < 8; ++c2) red0[li + r * 64 + c2] = num[r][c2];
  } else if (w == 3) {
#pragma unroll
    for (int r = 0; r < 8; ++r)
#pragma unroll
      for (int c2 = 0; c2 < 8; ++c2) red1[li + r * 64 + c2] = num[r][c2];
  }
  __syncthreads();
  if (w == 0) {
#pragma unroll
    for (int r = 0; r < 8; ++r)
#pragma unroll
      for (int c2 = 0; c2 < 8; ++c2) num[r][c2] += red0[li + r * 64 + c2];
  } else if (w == 1) {
#pragma unroll
    for (int r = 0; r < 8; ++r)
#pragma unroll
      for (int c2 = 0; c2 < 8; ++c2) num[r][c2] += red1[li + r * 64 + c2];
  }
  __syncthreads();
  if (w == 1) {
#pragma unroll
    for (int r = 0; r < 8; ++r)
#pragma unroll
      for (int c2 = 0; c2 < 8; ++c2) red0[li + r * 64 + c2] = num[r][c2];
  }
  __syncthreads();
  if (w == 0) {
    float* npo = NUMp + ((size_t)bh * kN + i0) * kDH;
#pragma unroll
    for (int r = 0; r < 8; ++r)
#pragma unroll
      for (int c2 = 0; c2 < 8; ++c2)
        atomicAdd(&npo[(size_t)(ig * 8 + r) * kDH + dg * 8 + c2],
                  num[r][c2] + red0[li + r * 64 + c2]);
  }
  if (dg == 0) {
#pragma unroll
    for (int r = 0; r < 8; ++r)
      atomicAdd(&DENp[bh * kN + i0 + ig * 8 + r], den[r]);
  }
}

// --------------------------------------------- normalize + head transpose
__global__ __launch_bounds__(256)
void normalize_attn(const float* __restrict__ NUMp, const float* __restrict__ DENp,
                    float* __restrict__ attn) {
  const int idx = blockIdx.x * 256 + threadIdx.x;   // [bh][i][d]
  const int d = idx & 63;
  const int i = (idx >> 6) & 255;
  const int bh = idx >> 14;
  const int b = bh >> 3, h = bh & 7;
  attn[((size_t)(b * kN + i)) * kDIM + h * kDH + d] = NUMp[idx] / DENp[bh * kN + i];
}

// ----------------------------------------------------------------- launch
extern "C" void kernel_launch(void* const* d_in, const int* in_sizes, int n_in,
                              void* d_out, int out_size, void* d_ws, size_t ws_size,
                              hipStream_t stream) {
  const float* x     = (const float*)d_in[0];
  const float* w_qkv = (const float*)d_in[1];
  const float* w_out = (const float*)d_in[2];
  const float* qw    = (const float*)d_in[3];
  const float* k1w   = (const float*)d_in[4];
  const float* k2w   = (const float*)d_in[5];

  float* ws   = (float*)d_ws;
  float* qkv  = ws + OF_QKV;
  float* E1p  = ws + OF_E1;    // overlays qkv (qkv dead after rms_layout)
  float* attn = ws + OF_ATTN;  // overlays qkv tail
  float* Q    = ws + OF_Q;
  float* K1   = ws + OF_K1;
  float* K2   = ws + OF_K2;
  float* V1   = ws + OF_V1;
  float* V2   = ws + OF_V2;
  float* E2p  = ws + OF_E2;
  float* E3p  = ws + OF_E3;
  float* NUMp = ws + OF_NUM;
  float* DENp = ws + OF_DEN;

  // zero the atomic accumulators (NUM + DEN are contiguous)
  hipMemsetAsync(NUMp, 0,
                 (size_t)(kBH * kN * kDH + kBH * kN) * sizeof(float), stream);

  // 1) qkv = x @ w_qkv          [512,512]x[512,2560]
  gemm_f32<<<dim3(kQKV / 64, kBN / 64), 256, 0, stream>>>(
      x, w_qkv, qkv, kBN, kQKV, kDIM);

  // 2) rmsnorm + split heads (qkv dead afterwards)
  rms_layout<<<dim3(kBN * kH), 64, 0, stream>>>(
      qkv, qw, k1w, k2w, Q, K1, K2, V1, V2);

  // 3) E1/E2/E3 = exp(clip(dot * 1/8))
  sims_exp<<<dim3(kBH, 3, 16), 256, 0, stream>>>(Q, K1, K2, E1p, E2p, E3p);

  // 4) main contraction
  strassen_main<<<dim3(256), 256, 0, stream>>>(E1p, E2p, E3p, V1, V2, NUMp, DENp);

  // 5) normalize + transpose back to [b,n,h*dh]
  normalize_attn<<<dim3(1024), 256, 0, stream>>>(NUMp, DENp, attn);

  // 6) out = attn @ w_out  -> d_out (FLOAT32 output)
  gemm_f32<<<dim3(kDIM / 64, kBN / 64), 256, 0, stream>>>(
      attn, w_out, (float*)d_out, kBN, kDIM, kDIM);
}

// Round 3
// 284.170 us; speedup vs baseline: 2.6309x; 2.6309x over previous
//
#include <hip/hip_runtime.h>
#include <hip/hip_bf16.h>

// StrassenMHA on MI355X — round 3: bf16-MFMA main contraction.
// Formulation: per (bh, d):  N_d = E2 @ B_d,  B_d[k,j] = e3[j,k]*v2[k,d];
//              num[i,d] = sum_j e1[i,j]*v1[j,d]*N_d[i,j]; d==64 => den (v2=v1=1).
// B=2, N=256, DIM=512, H=8, DH=64. Output f32.

namespace {
constexpr int kB = 2, kN = 256, kH = 8, kDH = 64;
constexpr int kBH = kB * kH;     // 16
constexpr int kBN = kB * kN;     // 512
constexpr int kDIM = 512;
constexpr int kQKV = 2560;
constexpr float kScale = 0.125f; // DH^-0.5
constexpr float kClamp = 40.0f;
constexpr float kEps = 1.1920928955078125e-07f;

typedef unsigned short u16;
typedef __attribute__((ext_vector_type(8))) short short8v;   // 8 x bf16 (4 VGPR)
typedef __attribute__((ext_vector_type(4))) float float4v;   // mfma acc

// ws layout (float-element offsets)
constexpr size_t OF_QKV  = 0;                                  // 1,310,720 (dead after rms)
constexpr size_t OF_E1   = 0;                                  // 1,048,576 overlays qkv
constexpr size_t OF_ATTN = OF_E1 + (size_t)kBH * kN * kN;      // 262,144 overlays qkv tail
constexpr size_t OF_Q    = (size_t)kBN * kQKV;                 // 1,310,720
constexpr size_t OF_K1   = OF_Q   + (size_t)kBH * kN * kDH;
constexpr size_t OF_K2   = OF_K1  + (size_t)kBH * kN * kDH;
constexpr size_t OF_V1   = OF_K2  + (size_t)kBH * kN * kDH;
constexpr size_t OF_V2   = OF_V1  + (size_t)kBH * kN * kDH;
constexpr size_t OF_E3   = OF_V2  + (size_t)kBH * kN * kDH;    // f32 1,048,576
constexpr size_t OF_E2B  = OF_E3  + (size_t)kBH * kN * kN;     // bf16 1,048,576 = 524,288 slots
constexpr size_t OF_NUM  = OF_E2B + (size_t)kBH * kN * kN / 2;
constexpr size_t OF_DEN  = OF_NUM + (size_t)kBH * kN * kDH;
// total = 4,460,544 floats = 17.8 MB
} // namespace

__device__ __forceinline__ unsigned int bf16_rne(float a) {
  unsigned int u = __float_as_uint(a);
  return (u + 0x7fffu + ((u >> 16) & 1u)) >> 16;
}
__device__ __forceinline__ unsigned int pk2_bf16(float a, float b) {
  unsigned int ua = bf16_rne(a);
  unsigned int ub = __float_as_uint(b);
  ub = (ub + 0x7fffu + ((ub >> 16) & 1u)) & 0xffff0000u;
  return ua | ub;
}

// ---------------------------------------------------------------- GEMM f32
__global__ __launch_bounds__(256)
void gemm_f32(const float* __restrict__ A, const float* __restrict__ Bm,
              float* __restrict__ C, int M, int N, int K) {
  __shared__ __align__(16) float As[16][68];
  __shared__ __align__(16) float Bs[16][68];
  const int tx = threadIdx.x & 15, ty = threadIdx.x >> 4;
  const int n0 = blockIdx.x * 64, m0 = blockIdx.y * 64;
  float acc[4][4] = {};
  for (int k0 = 0; k0 < K; k0 += 16) {
    {
      const int m = threadIdx.x >> 2;
      const int kk = (threadIdx.x & 3) << 2;
      float4 v = *(const float4*)(A + (size_t)(m0 + m) * K + k0 + kk);
      As[kk + 0][m] = v.x; As[kk + 1][m] = v.y;
      As[kk + 2][m] = v.z; As[kk + 3][m] = v.w;
    }
    {
      const int kk = threadIdx.x >> 4;
      const int n = (threadIdx.x & 15) << 2;
      *(float4*)&Bs[kk][n] = *(const float4*)(Bm + (size_t)(k0 + kk) * N + n0 + n);
    }
    __syncthreads();
#pragma unroll
    for (int kk = 0; kk < 16; ++kk) {
      float4 a4 = *(const float4*)&As[kk][ty << 2];
      float4 b4 = *(const float4*)&Bs[kk][tx << 2];
      const float av[4] = {a4.x, a4.y, a4.z, a4.w};
      const float bv[4] = {b4.x, b4.y, b4.z, b4.w};
#pragma unroll
      for (int i = 0; i < 4; ++i)
#pragma unroll
        for (int j = 0; j < 4; ++j)
          acc[i][j] = fmaf(av[i], bv[j], acc[i][j]);
    }
    __syncthreads();
  }
#pragma unroll
  for (int i = 0; i < 4; ++i) {
    float* cp = C + (size_t)(m0 + (ty << 2) + i) * N + n0 + (tx << 2);
#pragma unroll
    for (int j = 0; j < 4; ++j) cp[j] = acc[i][j];
  }
}

// ------------------------------------------------- RMSNorm + head split
__global__ __launch_bounds__(64)
void rms_layout(const float* __restrict__ qkv,
                const float* __restrict__ wq, const float* __restrict__ wk1,
                const float* __restrict__ wk2,
                float* __restrict__ Q, float* __restrict__ K1,
                float* __restrict__ K2, float* __restrict__ V1,
                float* __restrict__ V2) {
  const int bnh = blockIdx.x;
  const int h = bnh & 7;
  const int bn = bnh >> 3;
  const int b = bn >> 8;
  const int n = bn & 255;
  const int d = threadIdx.x;
  const float* row = qkv + (size_t)bn * kQKV;
  const int base = h * 64 + d;
  float q  = row[0 * 512 + base];
  float k1 = row[1 * 512 + base];
  float k2 = row[2 * 512 + base];
  float v1 = row[3 * 512 + base];
  float v2 = row[4 * 512 + base];
  float sq = q * q, s1 = k1 * k1, s2 = k2 * k2;
#pragma unroll
  for (int m = 32; m >= 1; m >>= 1) {
    sq += __shfl_xor(sq, m);
    s1 += __shfl_xor(s1, m);
    s2 += __shfl_xor(s2, m);
  }
  const float rq = rsqrtf(sq * (1.0f / 64) + kEps);
  const float r1 = rsqrtf(s1 * (1.0f / 64) + kEps);
  const float r2 = rsqrtf(s2 * (1.0f / 64) + kEps);
  const int bh = b * kH + h;
  const size_t o = ((size_t)bh * kN + n) * kDH + d;
  Q[o]  = q * rq * wq[d];
  K1[o] = k1 * r1 * wk1[d];
  K2[o] = k2 * r2 * wk2[d];
  V1[o] = v1;
  V2[o] = v2;
}

// ------------------------------------------------- E = exp(clip(dot/8))
// type 0: Q.K1 -> E1 (f32) ; type 1: Q.K2 -> E2b (bf16) ; type 2: K1.K2 -> E3 (f32)
__global__ __launch_bounds__(256)
void sims_exp(const float* __restrict__ Q, const float* __restrict__ K1,
              const float* __restrict__ K2, float* __restrict__ E1,
              u16* __restrict__ E2b, float* __restrict__ E3) {
  __shared__ __align__(16) float As[64][68];
  __shared__ __align__(16) float Bs[64][68];
  const int bh = blockIdx.x;
  const int type = blockIdx.y;
  const int i0 = (blockIdx.z >> 2) * 64;
  const int j0 = (blockIdx.z & 3) * 64;
  const float* Ap = (type == 2 ? K1 : Q) + ((size_t)bh * kN + i0) * kDH;
  const float* Bp = (type == 0 ? K1 : K2) + ((size_t)bh * kN + j0) * kDH;
  const int t = threadIdx.x;
#pragma unroll
  for (int c = 0; c < 16; ++c) {
    int idx = c * 256 + t;
    int i = idx >> 6, k = idx & 63;
    As[k][i] = Ap[(size_t)i * kDH + k];
    Bs[k][i] = Bp[(size_t)i * kDH + k];
  }
  __syncthreads();
  const int tx = t & 15, ty = t >> 4;
  float acc[4][4] = {};
#pragma unroll 4
  for (int k = 0; k < 64; ++k) {
    float4 a4 = *(const float4*)&As[k][ty << 2];
    float4 b4 = *(const float4*)&Bs[k][tx << 2];
    const float av[4] = {a4.x, a4.y, a4.z, a4.w};
    const float bv[4] = {b4.x, b4.y, b4.z, b4.w};
#pragma unroll
    for (int i = 0; i < 4; ++i)
#pragma unroll
      for (int j = 0; j < 4; ++j)
        acc[i][j] = fmaf(av[i], bv[j], acc[i][j]);
  }
  if (type != 1) {
    float* Ep = (type == 0 ? E1 : E3) + (size_t)bh * kN * kN;
#pragma unroll
    for (int i = 0; i < 4; ++i) {
      float* ep = Ep + (size_t)(i0 + (ty << 2) + i) * kN + j0 + (tx << 2);
#pragma unroll
      for (int j = 0; j < 4; ++j) {
        float s = acc[i][j] * kScale;
        s = fminf(fmaxf(s, -kClamp), kClamp);
        ep[j] = expf(s);
      }
    }
  } else {
    u16* Ep = E2b + (size_t)bh * kN * kN;
#pragma unroll
    for (int i = 0; i < 4; ++i) {
      u16* ep = Ep + (size_t)(i0 + (ty << 2) + i) * kN + j0 + (tx << 2);
#pragma unroll
      for (int j = 0; j < 4; ++j) {
        float s = acc[i][j] * kScale;
        s = fminf(fmaxf(s, -kClamp), kClamp);
        ep[j] = (u16)bf16_rne(expf(s));
      }
    }
  }
}

// ---------------------------------------------------------- main contraction (MFMA)
// grid (65, 16): x = d (64 => denominator column), y = bh. 256 threads, 4 waves.
// Wave w owns i in [w*64, w*64+64). j-tiles of 64, k-steps of 64.
__global__ __launch_bounds__(256)
void strassen_mfma(const u16* __restrict__ E2b, const float* __restrict__ E1,
                   const float* __restrict__ E3, const float* __restrict__ V1,
                   const float* __restrict__ V2, float* __restrict__ NUM,
                   float* __restrict__ DEN) {
  __shared__ __align__(16) u16 Bsh[64][72];   // [j][k] bf16, row 144B (16B-aligned, 2-way banks)
  __shared__ float v2col[256];

  const int d = blockIdx.x;     // 0..64
  const int bh = blockIdx.y;    // 0..15
  const int t = threadIdx.x;
  const int lane = t & 63;
  const int w = t >> 6;
  const int lrow = lane & 15;   // A-row / B-col / D-col selector
  const int lk = lane >> 4;     // k-group / D-row-group selector
  const int i0 = w * 64;

  // stage v2 column (or ones for the denominator block)
  v2col[t] = (d < 64) ? V2[((size_t)bh * kN + t) * kDH + d] : 1.0f;

  const u16* e2base = E2b + (size_t)bh * kN * kN;
  const float* e3base = E3 + (size_t)bh * kN * kN;
  const float* e1base = E1 + (size_t)bh * kN * kN;
  const float* v1base = V1 + (size_t)bh * kN * kDH;

  float p[4][4] = {};           // [m][r] num partials

  for (int jt = 0; jt < 4; ++jt) {
    float4v acc[4][4] = {};     // [m][nt]
    for (int ks = 0; ks < 4; ++ks) {
      const int k0 = ks * 64;
      __syncthreads();          // prior compute (and v2col on first iter) done
      // ---- stage B panel: Bs[j][k] = e3[j, k0+k] * v2col[k0+k], 64x64 bf16
      {
        const int j_loc = t & 63;
        const int kk = (t >> 6) << 4;                    // 0,16,32,48
        const float* er = e3base + ((size_t)(jt * 64 + j_loc)) * kN + k0 + kk;
        const float* vc = &v2col[k0 + kk];
        const float4 f0 = *(const float4*)(er + 0);
        const float4 f1 = *(const float4*)(er + 4);
        const float4 f2 = *(const float4*)(er + 8);
        const float4 f3 = *(const float4*)(er + 12);
        uint4 w0, w1;
        w0.x = pk2_bf16(f0.x * vc[0],  f0.y * vc[1]);
        w0.y = pk2_bf16(f0.z * vc[2],  f0.w * vc[3]);
        w0.z = pk2_bf16(f1.x * vc[4],  f1.y * vc[5]);
        w0.w = pk2_bf16(f1.z * vc[6],  f1.w * vc[7]);
        w1.x = pk2_bf16(f2.x * vc[8],  f2.y * vc[9]);
        w1.y = pk2_bf16(f2.z * vc[10], f2.w * vc[11]);
        w1.z = pk2_bf16(f3.x * vc[12], f3.y * vc[13]);
        w1.w = pk2_bf16(f3.z * vc[14], f3.w * vc[15]);
        *(uint4*)&Bsh[j_loc][kk]     = w0;
        *(uint4*)&Bsh[j_loc][kk + 8] = w1;
      }
      __syncthreads();
      // ---- MFMA: 2 sub-k (32 each) x 4 m x 4 n
#pragma unroll
      for (int sub = 0; sub < 2; ++sub) {
        const int kg = k0 + sub * 32 + lk * 8;
        short8v aF[4], bF[4];
#pragma unroll
        for (int m = 0; m < 4; ++m)
          aF[m] = *(const short8v*)(e2base + (size_t)(i0 + m * 16 + lrow) * kN + kg);
#pragma unroll
        for (int n = 0; n < 4; ++n)
          bF[n] = *(const short8v*)(&Bsh[n * 16 + lrow][sub * 32 + lk * 8]);
#pragma unroll
        for (int m = 0; m < 4; ++m)
#pragma unroll
          for (int n = 0; n < 4; ++n)
            acc[m][n] = __builtin_amdgcn_mfma_f32_16x16x32_bf16(
                aF[m], bF[n], acc[m][n], 0, 0, 0);
      }
    }
    // ---- epilogue for this j-tile: p[m][r] += e1[i,j]*v1[j,d]*acc
#pragma unroll
    for (int nt = 0; nt < 4; ++nt) {
      const int j = jt * 64 + nt * 16 + lrow;
      const float v1s = (d < 64) ? v1base[(size_t)j * kDH + d] : 1.0f;
#pragma unroll
      for (int m = 0; m < 4; ++m) {
        const float* e1r = e1base + (size_t)(i0 + m * 16 + lk * 4) * kN + j;
#pragma unroll
        for (int r = 0; r < 4; ++r)
          p[m][r] = fmaf(e1r[(size_t)r * kN] * v1s, acc[m][nt][r], p[m][r]);
      }
    }
  }

  // reduce over the 16 j-columns held by lanes (l&15), then write
#pragma unroll
  for (int m = 0; m < 4; ++m)
#pragma unroll
    for (int r = 0; r < 4; ++r) {
      float v = p[m][r];
      v += __shfl_xor(v, 1);
      v += __shfl_xor(v, 2);
      v += __shfl_xor(v, 4);
      v += __shfl_xor(v, 8);
      p[m][r] = v;
    }
  if (lrow == 0) {
    if (d < 64) {
      float* np = NUM + (size_t)bh * kN * kDH + d;
#pragma unroll
      for (int m = 0; m < 4; ++m)
#pragma unroll
        for (int r = 0; r < 4; ++r)
          np[(size_t)(i0 + m * 16 + lk * 4 + r) * kDH] = p[m][r];
    } else {
      float* dp = DEN + (size_t)bh * kN;
#pragma unroll
      for (int m = 0; m < 4; ++m)
#pragma unroll
        for (int r = 0; r < 4; ++r)
          dp[i0 + m * 16 + lk * 4 + r] = p[m][r];
    }
  }
}

// --------------------------------------------- normalize + head transpose
__global__ __launch_bounds__(256)
void normalize_attn(const float* __restrict__ NUMp, const float* __restrict__ DENp,
                    float* __restrict__ attn) {
  const int idx = blockIdx.x * 256 + threadIdx.x;   // [bh][i][d]
  const int d = idx & 63;
  const int i = (idx >> 6) & 255;
  const int bh = idx >> 14;
  const int b = bh >> 3, h = bh & 7;
  attn[((size_t)(b * kN + i)) * kDIM + h * kDH + d] = NUMp[idx] / DENp[bh * kN + i];
}

// ----------------------------------------------------------------- launch
extern "C" void kernel_launch(void* const* d_in, const int* in_sizes, int n_in,
                              void* d_out, int out_size, void* d_ws, size_t ws_size,
                              hipStream_t stream) {
  const float* x     = (const float*)d_in[0];
  const float* w_qkv = (const float*)d_in[1];
  const float* w_out = (const float*)d_in[2];
  const float* qw    = (const float*)d_in[3];
  const float* k1w   = (const float*)d_in[4];
  const float* k2w   = (const float*)d_in[5];

  float* ws   = (float*)d_ws;
  float* qkv  = ws + OF_QKV;
  float* E1p  = ws + OF_E1;
  float* attn = ws + OF_ATTN;
  float* Q    = ws + OF_Q;
  float* K1   = ws + OF_K1;
  float* K2   = ws + OF_K2;
  float* V1   = ws + OF_V1;
  float* V2   = ws + OF_V2;
  float* E3p  = ws + OF_E3;
  u16*   E2b  = (u16*)(ws + OF_E2B);
  float* NUMp = ws + OF_NUM;
  float* DENp = ws + OF_DEN;

  // 1) qkv = x @ w_qkv
  gemm_f32<<<dim3(kQKV / 64, kBN / 64), 256, 0, stream>>>(
      x, w_qkv, qkv, kBN, kQKV, kDIM);

  // 2) rmsnorm + split heads
  rms_layout<<<dim3(kBN * kH), 64, 0, stream>>>(
      qkv, qw, k1w, k2w, Q, K1, K2, V1, V2);

  // 3) E1 (f32), E2b (bf16), E3 (f32)
  sims_exp<<<dim3(kBH, 3, 16), 256, 0, stream>>>(Q, K1, K2, E1p, E2b, E3p);

  // 4) main contraction via MFMA; d==64 computes the denominator
  strassen_mfma<<<dim3(65, kBH), 256, 0, stream>>>(
      E2b, E1p, E3p, V1, V2, NUMp, DENp);

  // 5) normalize + transpose back
  normalize_attn<<<dim3(1024), 256, 0, stream>>>(NUMp, DENp, attn);

  // 6) out = attn @ w_out  -> d_out (f32)
  gemm_f32<<<dim3(kDIM / 64, kBN / 64), 256, 0, stream>>>(
      attn, w_out, (float*)d_out, kBN, kDIM, kDIM);
}